// Round 6
// baseline (90.969 us; speedup 1.0000x reference)
//
#include <hip/hip_runtime.h>
#include <hip/hip_fp16.h>

#define BLOCK 256
#define MAXB 64

typedef int   iv4 __attribute__((ext_vector_type(4)));
typedef float fv4 __attribute__((ext_vector_type(4)));

#define NT(p) __builtin_nontemporal_load(p)

// ---------------------------------------------------------------------------
// LJ energy from two packed site records {x,y,z, half2(sigma,eps)}.
// ---------------------------------------------------------------------------
__device__ __forceinline__ float energy4(float4 a, float4 b) {
    float dx = a.x - b.x, dy = a.y - b.y, dz = a.z - b.z;
    float r2 = dx * dx + dy * dy + dz * dz;
    __half2 ha = __builtin_bit_cast(__half2, a.w);
    __half2 hb = __builtin_bit_cast(__half2, b.w);
    float sig = 0.5f * (__low2float(ha) + __low2float(hb));
    float eps = sqrtf(__high2float(ha) * __high2float(hb));
    float s2 = sig * sig / r2;
    float x6 = s2 * s2 * s2;
    return 4.0f * eps * (x6 * x6 - x6);
}

struct PackedSites {
    const float4* __restrict__ site;
    __device__ __forceinline__ float energy(int s, int d) const {
        return energy4(site[s], site[d]);
    }
};

struct RawSites {
    const float* __restrict__ pos;   // [N,3]
    const float* __restrict__ par;   // [N,2] (sigma, eps)
    __device__ __forceinline__ float energy(int s, int d) const {
        float ax = pos[3 * s], ay = pos[3 * s + 1], az = pos[3 * s + 2];
        float bx = pos[3 * d], by = pos[3 * d + 1], bz = pos[3 * d + 2];
        float dx = ax - bx, dy = ay - by, dz = az - bz;
        float r2 = dx * dx + dy * dy + dz * dz;
        float sa = par[2 * s], ea = par[2 * s + 1];
        float sb = par[2 * d], eb = par[2 * d + 1];
        float sig = 0.5f * (sa + sb);
        float eps = sqrtf(ea * eb);
        float s2 = sig * sig / r2;
        float x6 = s2 * s2 * s2;
        return 4.0f * eps * (x6 * x6 - x6);
    }
};

// ---------------------------------------------------------------------------
// Pack sites: pos fp32 + (sigma,eps) fp16x2 into one 16B record per site.
// ---------------------------------------------------------------------------
__global__ __launch_bounds__(BLOCK) void pack_sites_kernel(
    const float* __restrict__ pos, const float* __restrict__ par,
    float4* __restrict__ site, int N)
{
    int i = blockIdx.x * BLOCK + threadIdx.x;
    if (i >= N) return;
    __half2 h = __floats2half2_rn(par[2 * i], par[2 * i + 1]);  // low=sigma, high=eps
    float4 v;
    v.x = pos[3 * i];
    v.y = pos[3 * i + 1];
    v.z = pos[3 * i + 2];
    v.w = __builtin_bit_cast(float, h);
    site[i] = v;
}

// ---------------------------------------------------------------------------
// Main kernel: each block owns a contiguous quad range. batch is SORTED, so
// most blocks see a single batch id (fast path). Fast path: x2 quad unroll,
// all 32 gathers loaded into statically-indexed locals FIRST (registers),
// then computed — forces the compiler to keep gathers in flight (round-2
// profile showed VGPR=32, i.e. a load-wait-use schedule with ~2 outstanding).
// ---------------------------------------------------------------------------
__global__ __launch_bounds__(BLOCK) void lj_main_kernel(
    const float4* __restrict__ site,
    const int* __restrict__ src,
    const int* __restrict__ dst,
    const int* __restrict__ batch,
    float* __restrict__ out,
    int nquads, int qpb, int B)
{
    __shared__ float bins[MAXB];
    for (int i = threadIdx.x; i < MAXB; i += BLOCK) bins[i] = 0.0f;
    __syncthreads();

    int q0 = blockIdx.x * qpb;
    int q1 = min(q0 + qpb, nquads);
    if (q0 < q1) {
        const int b_lo = batch[4 * q0];
        const int b_hi = batch[4 * q1 - 1];
        const iv4* s4p = (const iv4*)src;
        const iv4* d4p = (const iv4*)dst;
        PackedSites sites{site};

        if (b_lo == b_hi) {
            // -------- fast path: uniform batch id, no batch stream --------
            float acc = 0.0f;
            int q = q0 + (int)threadIdx.x;
            for (; q + BLOCK < q1; q += 2 * BLOCK) {
                iv4 s4 = NT(&s4p[q]);
                iv4 d4 = NT(&d4p[q]);
                iv4 s5 = NT(&s4p[q + BLOCK]);
                iv4 d5 = NT(&d4p[q + BLOCK]);
                // Load phase: 16 independent site-pair gathers into locals.
                float4 va0 = site[s4.x], wb0 = site[d4.x];
                float4 va1 = site[s4.y], wb1 = site[d4.y];
                float4 va2 = site[s4.z], wb2 = site[d4.z];
                float4 va3 = site[s4.w], wb3 = site[d4.w];
                float4 va4 = site[s5.x], wb4 = site[d5.x];
                float4 va5 = site[s5.y], wb5 = site[d5.y];
                float4 va6 = site[s5.z], wb6 = site[d5.z];
                float4 va7 = site[s5.w], wb7 = site[d5.w];
                // Compute phase.
                acc += energy4(va0, wb0);
                acc += energy4(va1, wb1);
                acc += energy4(va2, wb2);
                acc += energy4(va3, wb3);
                acc += energy4(va4, wb4);
                acc += energy4(va5, wb5);
                acc += energy4(va6, wb6);
                acc += energy4(va7, wb7);
            }
            for (; q < q1; q += 2 * BLOCK) {   // at most one tail quad/thread
                iv4 s4 = NT(&s4p[q]);
                iv4 d4 = NT(&d4p[q]);
                acc += sites.energy(s4.x, d4.x);
                acc += sites.energy(s4.y, d4.y);
                acc += sites.energy(s4.z, d4.z);
                acc += sites.energy(s4.w, d4.w);
            }
            #pragma unroll
            for (int off = 32; off > 0; off >>= 1) acc += __shfl_xor(acc, off);
            if ((threadIdx.x & 63) == 0) atomicAdd(&bins[b_lo], acc);
        } else {
            // -------- slow path: segment boundary inside this chunk --------
            const iv4* b4p = (const iv4*)batch;
            float acc = 0.0f;
            int bcur = -1;
            for (int q = q0 + (int)threadIdx.x; q < q1; q += BLOCK) {
                iv4 s4 = NT(&s4p[q]);
                iv4 d4 = NT(&d4p[q]);
                iv4 b4 = NT(&b4p[q]);
                int ss[4] = {s4.x, s4.y, s4.z, s4.w};
                int dd[4] = {d4.x, d4.y, d4.z, d4.w};
                int bb[4] = {b4.x, b4.y, b4.z, b4.w};
                #pragma unroll
                for (int j = 0; j < 4; ++j) {
                    int b = bb[j];
                    if (b != bcur) {
                        if (bcur >= 0) atomicAdd(&bins[bcur], acc);
                        bcur = b;
                        acc = 0.0f;
                    }
                    acc += sites.energy(ss[j], dd[j]);
                }
            }
            int b0 = __shfl(bcur, 0);
            bool uni = __all(bcur == b0);
            if (uni) {
                if (b0 >= 0) {
                    #pragma unroll
                    for (int off = 32; off > 0; off >>= 1) acc += __shfl_xor(acc, off);
                    if ((threadIdx.x & 63) == 0) atomicAdd(&bins[b0], acc);
                }
            } else if (bcur >= 0) {
                atomicAdd(&bins[bcur], acc);
            }
        }
    }
    __syncthreads();
    for (int i = threadIdx.x; i < MAXB && i < B; i += BLOCK) {
        float v = bins[i];
        if (v != 0.0f) unsafeAtomicAdd(&out[i], v);
    }
}

// Scalar range kernel: tail edges and generic fallback.
template <class S>
__global__ __launch_bounds__(BLOCK) void lj_range_kernel(
    S sites,
    const int* __restrict__ src,
    const int* __restrict__ dst,
    const int* __restrict__ batch,
    float* __restrict__ out,
    int e0, int E)
{
    int e = e0 + blockIdx.x * BLOCK + (int)threadIdx.x;
    if (e < E) {
        float c = sites.energy(src[e], dst[e]);
        unsafeAtomicAdd(&out[batch[e]], c);
    }
}

extern "C" void kernel_launch(void* const* d_in, const int* in_sizes, int n_in,
                              void* d_out, int out_size, void* d_ws, size_t ws_size,
                              hipStream_t stream) {
    const float* pos   = (const float*)d_in[0];   // [N,3] fp32
    const float* par   = (const float*)d_in[1];   // [N,2] fp32
    const int*   eidx  = (const int*)d_in[2];     // [2,E] int32
    const int*   batch = (const int*)d_in[3];     // [E] int32, sorted
    const int N = in_sizes[0] / 3;
    const int E = in_sizes[3];
    const int* src = eidx;
    const int* dst = eidx + E;
    float* out = (float*)d_out;
    const int B = out_size;

    (void)hipMemsetAsync(d_out, 0, (size_t)out_size * sizeof(float), stream);
    if (E <= 0 || B <= 0) return;

    if (ws_size >= (size_t)N * sizeof(float4) && B <= MAXB) {
        float4* site = (float4*)d_ws;
        pack_sites_kernel<<<(N + BLOCK - 1) / BLOCK, BLOCK, 0, stream>>>(pos, par, site, N);
        int nquads = E >> 2;
        int tail = E & 3;
        if (nquads > 0) {
            int qpb = 512;   // 2M quads -> ~3907 blocks (~2x oversubscription)
            int nb = (nquads + qpb - 1) / qpb;
            lj_main_kernel<<<nb, BLOCK, 0, stream>>>(site, src, dst, batch, out,
                                                     nquads, qpb, B);
        }
        if (tail) {
            PackedSites S{site};
            lj_range_kernel<PackedSites><<<1, BLOCK, 0, stream>>>(
                S, src, dst, batch, out, 4 * nquads, E);
        }
    } else {
        RawSites S{pos, par};
        lj_range_kernel<RawSites><<<(E + BLOCK - 1) / BLOCK, BLOCK, 0, stream>>>(
            S, src, dst, batch, out, 0, E);
    }
}

// Round 7
// 89.722 us; speedup vs baseline: 1.0139x; 1.0139x over previous
//
#include <hip/hip_runtime.h>
#include <hip/hip_fp16.h>

#define BLOCK 256
#define MAXB 64

typedef int   iv4 __attribute__((ext_vector_type(4)));
typedef float fv4 __attribute__((ext_vector_type(4)));

#define NT(p) __builtin_nontemporal_load(p)

#if __has_builtin(__builtin_amdgcn_make_buffer_rsrc) && \
    __has_builtin(__builtin_amdgcn_raw_buffer_load_b128)
#define USE_BUFFER 1
#else
#define USE_BUFFER 0
#endif

// ---------------------------------------------------------------------------
// LJ energy from two packed site records {x,y,z, half2(sigma,eps)}.
// ---------------------------------------------------------------------------
__device__ __forceinline__ float energy4(float4 a, float4 b) {
    float dx = a.x - b.x, dy = a.y - b.y, dz = a.z - b.z;
    float r2 = dx * dx + dy * dy + dz * dz;
    __half2 ha = __builtin_bit_cast(__half2, a.w);
    __half2 hb = __builtin_bit_cast(__half2, b.w);
    float sig = 0.5f * (__low2float(ha) + __low2float(hb));
    float eps = sqrtf(__high2float(ha) * __high2float(hb));
    float s2 = sig * sig / r2;
    float x6 = s2 * s2 * s2;
    return 4.0f * eps * (x6 * x6 - x6);
}

struct PackedSites {
    const float4* __restrict__ site;
    __device__ __forceinline__ float energy(int s, int d) const {
        return energy4(site[s], site[d]);
    }
};

struct RawSites {
    const float* __restrict__ pos;   // [N,3]
    const float* __restrict__ par;   // [N,2] (sigma, eps)
    __device__ __forceinline__ float energy(int s, int d) const {
        float ax = pos[3 * s], ay = pos[3 * s + 1], az = pos[3 * s + 2];
        float bx = pos[3 * d], by = pos[3 * d + 1], bz = pos[3 * d + 2];
        float dx = ax - bx, dy = ay - by, dz = az - bz;
        float r2 = dx * dx + dy * dy + dz * dz;
        float sa = par[2 * s], ea = par[2 * s + 1];
        float sb = par[2 * d], eb = par[2 * d + 1];
        float sig = 0.5f * (sa + sb);
        float eps = sqrtf(ea * eb);
        float s2 = sig * sig / r2;
        float x6 = s2 * s2 * s2;
        return 4.0f * eps * (x6 * x6 - x6);
    }
};

// ---------------------------------------------------------------------------
// Pack sites: pos fp32 + (sigma,eps) fp16x2 into one 16B record per site.
// ---------------------------------------------------------------------------
__global__ __launch_bounds__(BLOCK) void pack_sites_kernel(
    const float* __restrict__ pos, const float* __restrict__ par,
    float4* __restrict__ site, int N)
{
    int i = blockIdx.x * BLOCK + threadIdx.x;
    if (i >= N) return;
    __half2 h = __floats2half2_rn(par[2 * i], par[2 * i + 1]);  // low=sigma, high=eps
    float4 v;
    v.x = pos[3 * i];
    v.y = pos[3 * i + 1];
    v.z = pos[3 * i + 2];
    v.w = __builtin_bit_cast(float, h);
    site[i] = v;
}

// ---------------------------------------------------------------------------
// Main kernel. Fast path gathers go through SRSRC buffer loads with aux=1
// (sc0 -> agent scope -> L1 bypass): the per-CU L1 miss queue (~64 MSHRs /
// ~200cy L2 latency = 0.32 lines/cy/CU, exactly the measured 0.326) is the
// bottleneck; L2 request queues are deeper. num_records=0xFFFFFFFF disables
// the HW bounds check (prior NaN failures = zero-filled loads, consistent
// with an OOB'ing descriptor). If the bypass path still returns zeros,
// energy4 yields 0*0/0 = NaN and the per-thread fallback recomputes with
// plain loads — correctness cannot regress, duration tells the diagnosis.
// ---------------------------------------------------------------------------
__global__ __launch_bounds__(BLOCK) void lj_main_kernel(
    const float4* __restrict__ site,
    const int* __restrict__ src,
    const int* __restrict__ dst,
    const int* __restrict__ batch,
    float* __restrict__ out,
    int nquads, int qpb, int B)
{
    __shared__ float bins[MAXB];
    for (int i = threadIdx.x; i < MAXB; i += BLOCK) bins[i] = 0.0f;
    __syncthreads();

    int q0 = blockIdx.x * qpb;
    int q1 = min(q0 + qpb, nquads);
    if (q0 < q1) {
        const int b_lo = batch[4 * q0];
        const int b_hi = batch[4 * q1 - 1];
        const iv4* s4p = (const iv4*)src;
        const iv4* d4p = (const iv4*)dst;
        PackedSites sites{site};

        if (b_lo == b_hi) {
            // -------- fast path: uniform batch id, no batch stream --------
#if USE_BUFFER
            __amdgpu_buffer_rsrc_t rsrc = __builtin_amdgcn_make_buffer_rsrc(
                (void*)site, (short)0, 0xFFFFFFFFu, 0x00020000);
            #define GATHER16(ix) __builtin_bit_cast(float4, \
                __builtin_amdgcn_raw_buffer_load_b128(rsrc, (int)((ix) << 4), 0, 1))
#else
            #define GATHER16(ix) site[(ix)]
#endif
            float acc = 0.0f;
            for (int q = q0 + (int)threadIdx.x; q < q1; q += BLOCK) {
                iv4 s4 = NT(&s4p[q]);
                iv4 d4 = NT(&d4p[q]);
                float4 a0 = GATHER16(s4.x), b0 = GATHER16(d4.x);
                float4 a1 = GATHER16(s4.y), b1 = GATHER16(d4.y);
                float4 a2 = GATHER16(s4.z), b2 = GATHER16(d4.z);
                float4 a3 = GATHER16(s4.w), b3 = GATHER16(d4.w);
                acc += energy4(a0, b0);
                acc += energy4(a1, b1);
                acc += energy4(a2, b2);
                acc += energy4(a3, b3);
            }
            #undef GATHER16
            // Self-check: zero-filled (broken) gathers produce NaN (0*0/0).
            // Recompute this thread's range with plain loads if so.
            if (acc != acc) {
                acc = 0.0f;
                for (int q = q0 + (int)threadIdx.x; q < q1; q += BLOCK) {
                    iv4 s4 = NT(&s4p[q]);
                    iv4 d4 = NT(&d4p[q]);
                    acc += sites.energy(s4.x, d4.x);
                    acc += sites.energy(s4.y, d4.y);
                    acc += sites.energy(s4.z, d4.z);
                    acc += sites.energy(s4.w, d4.w);
                }
            }
            #pragma unroll
            for (int off = 32; off > 0; off >>= 1) acc += __shfl_xor(acc, off);
            if ((threadIdx.x & 63) == 0) atomicAdd(&bins[b_lo], acc);
        } else {
            // -------- slow path: segment boundary inside this chunk --------
            const iv4* b4p = (const iv4*)batch;
            float acc = 0.0f;
            int bcur = -1;
            for (int q = q0 + (int)threadIdx.x; q < q1; q += BLOCK) {
                iv4 s4 = NT(&s4p[q]);
                iv4 d4 = NT(&d4p[q]);
                iv4 b4 = NT(&b4p[q]);
                int ss[4] = {s4.x, s4.y, s4.z, s4.w};
                int dd[4] = {d4.x, d4.y, d4.z, d4.w};
                int bb[4] = {b4.x, b4.y, b4.z, b4.w};
                #pragma unroll
                for (int j = 0; j < 4; ++j) {
                    int b = bb[j];
                    if (b != bcur) {
                        if (bcur >= 0) atomicAdd(&bins[bcur], acc);
                        bcur = b;
                        acc = 0.0f;
                    }
                    acc += sites.energy(ss[j], dd[j]);
                }
            }
            int b0 = __shfl(bcur, 0);
            bool uni = __all(bcur == b0);
            if (uni) {
                if (b0 >= 0) {
                    #pragma unroll
                    for (int off = 32; off > 0; off >>= 1) acc += __shfl_xor(acc, off);
                    if ((threadIdx.x & 63) == 0) atomicAdd(&bins[b0], acc);
                }
            } else if (bcur >= 0) {
                atomicAdd(&bins[bcur], acc);
            }
        }
    }
    __syncthreads();
    for (int i = threadIdx.x; i < MAXB && i < B; i += BLOCK) {
        float v = bins[i];
        if (v != 0.0f) unsafeAtomicAdd(&out[i], v);
    }
}

// Scalar range kernel: tail edges and generic fallback.
template <class S>
__global__ __launch_bounds__(BLOCK) void lj_range_kernel(
    S sites,
    const int* __restrict__ src,
    const int* __restrict__ dst,
    const int* __restrict__ batch,
    float* __restrict__ out,
    int e0, int E)
{
    int e = e0 + blockIdx.x * BLOCK + (int)threadIdx.x;
    if (e < E) {
        float c = sites.energy(src[e], dst[e]);
        unsafeAtomicAdd(&out[batch[e]], c);
    }
}

extern "C" void kernel_launch(void* const* d_in, const int* in_sizes, int n_in,
                              void* d_out, int out_size, void* d_ws, size_t ws_size,
                              hipStream_t stream) {
    const float* pos   = (const float*)d_in[0];   // [N,3] fp32
    const float* par   = (const float*)d_in[1];   // [N,2] fp32
    const int*   eidx  = (const int*)d_in[2];     // [2,E] int32
    const int*   batch = (const int*)d_in[3];     // [E] int32, sorted
    const int N = in_sizes[0] / 3;
    const int E = in_sizes[3];
    const int* src = eidx;
    const int* dst = eidx + E;
    float* out = (float*)d_out;
    const int B = out_size;

    (void)hipMemsetAsync(d_out, 0, (size_t)out_size * sizeof(float), stream);
    if (E <= 0 || B <= 0) return;

    if (ws_size >= (size_t)N * sizeof(float4) && B <= MAXB) {
        float4* site = (float4*)d_ws;
        pack_sites_kernel<<<(N + BLOCK - 1) / BLOCK, BLOCK, 0, stream>>>(pos, par, site, N);
        int nquads = E >> 2;
        int tail = E & 3;
        if (nquads > 0) {
            int qpb = 512;
            int nb = (nquads + qpb - 1) / qpb;
            lj_main_kernel<<<nb, BLOCK, 0, stream>>>(site, src, dst, batch, out,
                                                     nquads, qpb, B);
        }
        if (tail) {   // E % 4 == 0 for this problem -> normally no launch
            PackedSites S{site};
            lj_range_kernel<PackedSites><<<1, BLOCK, 0, stream>>>(
                S, src, dst, batch, out, 4 * nquads, E);
        }
    } else {
        RawSites S{pos, par};
        lj_range_kernel<RawSites><<<(E + BLOCK - 1) / BLOCK, BLOCK, 0, stream>>>(
            S, src, dst, batch, out, 0, E);
    }
}